// Round 2
// baseline (1678.632 us; speedup 1.0000x reference)
//
#include <hip/hip_runtime.h>
#include <math.h>

#define D 64

static inline size_t align256(size_t x) { return (x + 255) & ~(size_t)255; }

__global__ void k_deg(const int* __restrict__ to, int E, unsigned* __restrict__ deg) {
    int st = gridDim.x * blockDim.x;
    for (int e = blockIdx.x * blockDim.x + threadIdx.x; e < E; e += st)
        atomicAdd(&deg[to[e]], 1u);
}

__global__ void k_dis(const unsigned* __restrict__ deg, int N, float* __restrict__ dis) {
    int n = blockIdx.x * blockDim.x + threadIdx.x;
    if (n < N) {
        unsigned dg = deg[n];
        dis[n] = dg ? 1.0f / sqrtf((float)dg) : 0.0f;
    }
}

__global__ void k_norm(const int* __restrict__ frm, const int* __restrict__ to,
                       const float* __restrict__ w, const float* __restrict__ dis,
                       int E, float* __restrict__ norm, float* __restrict__ s) {
    int st = gridDim.x * blockDim.x;
    for (int e = blockIdx.x * blockDim.x + threadIdx.x; e < E; e += st) {
        float nv = dis[frm[e]] * dis[to[e]] * w[e];
        norm[e] = nv;
        unsafeAtomicAdd(&s[to[e]], nv);
    }
}

// x = emb; out0[0:N*D) = emb0; out1 (concat tensor) cols 0..63 = emb0
__global__ void k_emb_init(const float* __restrict__ emb, float* __restrict__ x,
                           float* __restrict__ out, int N) {
    int total = N * (D / 4);  // in float4 units
    int st = gridDim.x * blockDim.x;
    const float4* e4 = (const float4*)emb;
    float4* x4 = (float4*)x;
    float4* o4 = (float4*)out;
    for (int j = blockIdx.x * blockDim.x + threadIdx.x; j < total; j += st) {
        float4 v = e4[j];
        x4[j] = v;
        o4[j] = v;                      // output 0: emb0
        int i = j >> 4;                 // node (16 float4 per 64-float row)
        int c = j & 15;
        // output 1 row i: cols 0..63 = emb0[i]  (cols 64..127 written by last k_update)
        o4[(size_t)N * (D / 4) + (size_t)i * 32 + c] = v;
    }
}

// g[to] += norm_e * x[frm];  one wave (64 lanes = 64 features) per edge iteration
__global__ void k_scatter(const int* __restrict__ frm, const int* __restrict__ to,
                          const float* __restrict__ norm, const float* __restrict__ x,
                          float* __restrict__ g, int E) {
    int lane = threadIdx.x & 63;
    int wid = (blockIdx.x * blockDim.x + threadIdx.x) >> 6;
    int nw = (gridDim.x * blockDim.x) >> 6;
    for (int e = wid; e < E; e += nw) {
        int f = frm[e], t = to[e];
        float nv = norm[e];
        unsafeAtomicAdd(&g[(size_t)t * D + lane], nv * x[(size_t)f * D + lane]);
    }
}

// x_out[i] = leaky_relu((g+x)@W1^T + (g*x)@W2^T + (s+1)*b1 + s*b2)
__global__ __launch_bounds__(256) void k_update(
        const float* __restrict__ g, const float* __restrict__ xin,
        const float* __restrict__ s,
        const float* __restrict__ W1, const float* __restrict__ b1,
        const float* __restrict__ W2, const float* __restrict__ b2,
        int N, float* __restrict__ xout, int ostride) {
    __shared__ float w1t[D * D];
    __shared__ float w2t[D * D];
    __shared__ float b1s[D];
    __shared__ float b2s[D];
    for (int idx = threadIdx.x; idx < D * D; idx += blockDim.x) {
        int r = idx >> 6, c = idx & 63;
        w1t[c * D + r] = W1[idx];   // store transposed: [c][r]
        w2t[c * D + r] = W2[idx];
    }
    if (threadIdx.x < D) {
        b1s[threadIdx.x] = b1[threadIdx.x];
        b2s[threadIdx.x] = b2[threadIdx.x];
    }
    __syncthreads();
    int lane = threadIdx.x & 63;
    int wid = (blockIdx.x * blockDim.x + threadIdx.x) >> 6;
    int nw = (gridDim.x * blockDim.x) >> 6;
    float bb1 = b1s[lane], bb2 = b2s[lane];
    for (int i = wid; i < N; i += nw) {
        float xv = xin[(size_t)i * D + lane];
        float gv = g[(size_t)i * D + lane];
        float h1 = xv + gv;
        float h2 = xv * gv;
        float sv = s[i];
        float acc = (sv + 1.0f) * bb1 + sv * bb2;
#pragma unroll
        for (int c = 0; c < D; ++c) {
            acc = fmaf(__shfl(h1, c), w1t[c * D + lane], acc);
            acc = fmaf(__shfl(h2, c), w2t[c * D + lane], acc);
        }
        float v = acc > 0.0f ? acc : 0.01f * acc;
        xout[(size_t)i * ostride + lane] = v;
    }
}

extern "C" void kernel_launch(void* const* d_in, const int* in_sizes, int n_in,
                              void* d_out, int out_size, void* d_ws, size_t ws_size,
                              hipStream_t stream) {
    const int* eidx = (const int*)d_in[0];
    const float* w = (const float*)d_in[1];
    const float* emb = (const float*)d_in[2];
    const float* W1 = (const float*)d_in[3];
    const float* b1 = (const float*)d_in[4];
    const float* W2 = (const float*)d_in[5];
    const float* b2 = (const float*)d_in[6];

    int E = in_sizes[1];
    int N = in_sizes[2] / D;
    int L = in_sizes[3] / (D * D);
    const int* frm = eidx;
    const int* to = eidx + E;

    char* ws = (char*)d_ws;
    size_t off = 0;
    float* x = (float*)(ws + off);    off += align256((size_t)N * D * 4);
    float* g = (float*)(ws + off);    off += align256((size_t)N * D * 4);
    float* norm = (float*)(ws + off); off += align256((size_t)E * 4);
    float* s = (float*)(ws + off);    off += align256((size_t)N * 4);
    float* dis = (float*)(ws + off);  off += align256((size_t)N * 4);
    unsigned* deg = (unsigned*)(ws + off); off += align256((size_t)N * 4);

    float* out = (float*)d_out;

    hipMemsetAsync(deg, 0, (size_t)N * 4, stream);
    hipMemsetAsync(s, 0, (size_t)N * 4, stream);

    k_deg<<<2048, 256, 0, stream>>>(to, E, deg);
    k_dis<<<(N + 255) / 256, 256, 0, stream>>>(deg, N, dis);
    k_norm<<<2048, 256, 0, stream>>>(frm, to, w, dis, E, norm, s);
    k_emb_init<<<2048, 256, 0, stream>>>(emb, x, out, N);

    for (int l = 0; l < L; ++l) {
        hipMemsetAsync(g, 0, (size_t)N * D * 4, stream);
        k_scatter<<<4096, 256, 0, stream>>>(frm, to, norm, x, g, E);
        float* optr;
        int ostride;
        if (l == L - 1) {
            optr = out + (size_t)N * D + D;  // out tensor (output 1), col offset 64
            ostride = 2 * D;
        } else {
            optr = x;
            ostride = D;
        }
        k_update<<<1024, 256, 0, stream>>>(g, x, s,
                                           W1 + (size_t)l * D * D, b1 + (size_t)l * D,
                                           W2 + (size_t)l * D * D, b2 + (size_t)l * D,
                                           N, optr, ostride);
    }
}

// Round 3
// 1620.867 us; speedup vs baseline: 1.0356x; 1.0356x over previous
//
#include <hip/hip_runtime.h>
#include <math.h>

#define D 64

static inline size_t align256(size_t x) { return (x + 255) & ~(size_t)255; }

__global__ void k_deg(const int* __restrict__ to, int E, unsigned* __restrict__ deg) {
    int st = gridDim.x * blockDim.x;
    for (int e = blockIdx.x * blockDim.x + threadIdx.x; e < E; e += st)
        atomicAdd(&deg[to[e]], 1u);
}

__global__ void k_dis(const unsigned* __restrict__ deg, int N, float* __restrict__ dis) {
    int n = blockIdx.x * blockDim.x + threadIdx.x;
    if (n < N) {
        unsigned dg = deg[n];
        dis[n] = dg ? 1.0f / sqrtf((float)dg) : 0.0f;
    }
}

// single-block exclusive scan of deg[0..N) -> rowptr[0..N], cursor[0..N)
__global__ __launch_bounds__(1024) void k_scan(const unsigned* __restrict__ deg, int N,
                                               int* __restrict__ rowptr, int* __restrict__ cursor) {
    __shared__ unsigned partial[1024];
    int t = threadIdx.x;
    int chunk = (N + 1023) >> 10;
    int lo = t * chunk;
    int hi = lo + chunk; if (hi > N) hi = N;
    unsigned sum = 0;
    for (int i = lo; i < hi; ++i) sum += deg[i];
    partial[t] = sum;
    __syncthreads();
    // Hillis-Steele inclusive scan over 1024 partials
    for (int ofs = 1; ofs < 1024; ofs <<= 1) {
        unsigned v = (t >= ofs) ? partial[t - ofs] : 0u;
        __syncthreads();
        partial[t] += v;
        __syncthreads();
    }
    unsigned run = partial[t] - sum;  // exclusive base for this thread's chunk
    for (int i = lo; i < hi; ++i) {
        rowptr[i] = (int)run;
        cursor[i] = (int)run;
        run += deg[i];
    }
    if (hi == N && lo <= N) {
        if (lo < N || t == 0) rowptr[N] = (int)run;  // thread owning the last chunk writes total
    }
}

// bucket-fill: er[pos] = {frm, norm} grouped by target node
__global__ void k_fill(const int* __restrict__ frm, const int* __restrict__ to,
                       const float* __restrict__ w, const float* __restrict__ dis,
                       int E, int* __restrict__ cursor, int2* __restrict__ er) {
    int st = gridDim.x * blockDim.x;
    for (int e = blockIdx.x * blockDim.x + threadIdx.x; e < E; e += st) {
        int f = frm[e], t = to[e];
        float nv = dis[f] * dis[t] * w[e];
        int pos = atomicAdd(&cursor[t], 1);
        int2 r; r.x = f; r.y = __float_as_int(nv);
        er[pos] = r;
    }
}

// x = emb; out0[0:N*D) = emb0; out1 (concat tensor) cols 0..63 = emb0
__global__ void k_emb_init(const float* __restrict__ emb, float* __restrict__ x,
                           float* __restrict__ out, int N) {
    int total = N * (D / 4);
    int st = gridDim.x * blockDim.x;
    const float4* e4 = (const float4*)emb;
    float4* x4 = (float4*)x;
    float4* o4 = (float4*)out;
    for (int j = blockIdx.x * blockDim.x + threadIdx.x; j < total; j += st) {
        float4 v = e4[j];
        x4[j] = v;
        o4[j] = v;                              // output 0: emb0
        int i = j >> 4;
        int c = j & 15;
        o4[(size_t)N * (D / 4) + (size_t)i * 32 + c] = v;  // output 1 cols 0..63
    }
}

// fused per-layer: one wave per node.
// g = sum_e norm_e * x[frm_e]; s = sum_e norm_e;
// x_out = leaky_relu((g+x)@W1^T + (g*x)@W2^T + (s+1)*b1 + s*b2)
__global__ __launch_bounds__(256) void k_layer(
        const int* __restrict__ rowptr, const int2* __restrict__ er,
        const float* __restrict__ xin,
        const float* __restrict__ W1, const float* __restrict__ b1,
        const float* __restrict__ W2, const float* __restrict__ b2,
        int N, float* __restrict__ xout, int ostride) {
    __shared__ float w1t[D * D];
    __shared__ float w2t[D * D];
    __shared__ float b1s[D];
    __shared__ float b2s[D];
    for (int idx = threadIdx.x; idx < D * D; idx += blockDim.x) {
        int r = idx >> 6, c = idx & 63;
        w1t[c * D + r] = W1[idx];
        w2t[c * D + r] = W2[idx];
    }
    if (threadIdx.x < D) {
        b1s[threadIdx.x] = b1[threadIdx.x];
        b2s[threadIdx.x] = b2[threadIdx.x];
    }
    __syncthreads();
    int lane = threadIdx.x & 63;
    int wid = (blockIdx.x * blockDim.x + threadIdx.x) >> 6;
    int nw = (gridDim.x * blockDim.x) >> 6;
    float bb1 = b1s[lane], bb2 = b2s[lane];
    for (int i = wid; i < N; i += nw) {
        int off0 = rowptr[i], off1 = rowptr[i + 1];
        float gacc = 0.0f, sv = 0.0f;
        for (int base = off0; base < off1; base += 64) {
            int n = off1 - base; if (n > 64) n = 64;
            int2 r; r.x = 0; r.y = 0;
            if (lane < n) r = er[base + lane];
            for (int j = 0; j < n; ++j) {
                int f = __shfl(r.x, j);
                float nv = __int_as_float(__shfl(r.y, j));
                gacc = fmaf(nv, xin[((size_t)f << 6) + lane], gacc);
                sv += nv;
            }
        }
        float xv = xin[((size_t)i << 6) + lane];
        float h1 = xv + gacc;
        float h2 = xv * gacc;
        float acc = (sv + 1.0f) * bb1 + sv * bb2;
#pragma unroll
        for (int c = 0; c < D; ++c) {
            acc = fmaf(__shfl(h1, c), w1t[c * D + lane], acc);
            acc = fmaf(__shfl(h2, c), w2t[c * D + lane], acc);
        }
        float v = acc > 0.0f ? acc : 0.01f * acc;
        xout[(size_t)i * ostride + lane] = v;
    }
}

extern "C" void kernel_launch(void* const* d_in, const int* in_sizes, int n_in,
                              void* d_out, int out_size, void* d_ws, size_t ws_size,
                              hipStream_t stream) {
    const int* eidx = (const int*)d_in[0];
    const float* w = (const float*)d_in[1];
    const float* emb = (const float*)d_in[2];
    const float* W1 = (const float*)d_in[3];
    const float* b1 = (const float*)d_in[4];
    const float* W2 = (const float*)d_in[5];
    const float* b2 = (const float*)d_in[6];

    int E = in_sizes[1];
    int N = in_sizes[2] / D;
    int L = in_sizes[3] / (D * D);
    const int* frm = eidx;
    const int* to = eidx + E;

    char* ws = (char*)d_ws;
    size_t off = 0;
    float* x0 = (float*)(ws + off);     off += align256((size_t)N * D * 4);
    float* x1 = (float*)(ws + off);     off += align256((size_t)N * D * 4);
    int2* er = (int2*)(ws + off);       off += align256((size_t)E * 8);
    int* rowptr = (int*)(ws + off);     off += align256((size_t)(N + 1) * 4);
    int* cursor = (int*)(ws + off);     off += align256((size_t)N * 4);
    unsigned* deg = (unsigned*)(ws + off); off += align256((size_t)N * 4);
    float* dis = (float*)(ws + off);    off += align256((size_t)N * 4);

    float* out = (float*)d_out;

    hipMemsetAsync(deg, 0, (size_t)N * 4, stream);

    k_deg<<<2048, 256, 0, stream>>>(to, E, deg);
    k_dis<<<(N + 255) / 256, 256, 0, stream>>>(deg, N, dis);
    k_scan<<<1, 1024, 0, stream>>>(deg, N, rowptr, cursor);
    k_fill<<<2048, 256, 0, stream>>>(frm, to, w, dis, E, cursor, er);
    k_emb_init<<<2048, 256, 0, stream>>>(emb, x0, out, N);

    float* xin = x0;
    float* xalt = x1;
    for (int l = 0; l < L; ++l) {
        float* optr;
        int ostride;
        if (l == L - 1) {
            optr = out + (size_t)N * D + D;  // output 1, cols 64..127
            ostride = 2 * D;
        } else {
            optr = xalt;
            ostride = D;
        }
        k_layer<<<2048, 256, 0, stream>>>(rowptr, er, xin,
                                          W1 + (size_t)l * D * D, b1 + (size_t)l * D,
                                          W2 + (size_t)l * D * D, b2 + (size_t)l * D,
                                          N, optr, ostride);
        float* t = xin; xin = xalt; xalt = t;
    }
}

// Round 4
// 1025.865 us; speedup vs baseline: 1.6363x; 1.5800x over previous
//
#include <hip/hip_runtime.h>
#include <math.h>

#define D 64

static inline size_t align256(size_t x) { return (x + 255) & ~(size_t)255; }

__global__ void k_deg(const int* __restrict__ to, int E, unsigned* __restrict__ deg) {
    int st = gridDim.x * blockDim.x;
    for (int e = blockIdx.x * blockDim.x + threadIdx.x; e < E; e += st)
        atomicAdd(&deg[to[e]], 1u);
}

__global__ void k_dis(const unsigned* __restrict__ deg, int N, float* __restrict__ dis) {
    int n = blockIdx.x * blockDim.x + threadIdx.x;
    if (n < N) {
        unsigned dg = deg[n];
        dis[n] = dg ? 1.0f / sqrtf((float)dg) : 0.0f;
    }
}

// ---- chunked exclusive scan of deg -> rowptr/cursor ----
// chunk = ceil(N/1024) so nchunks <= 1024
__global__ void k_chunksum(const unsigned* __restrict__ deg, int N, int chunk,
                           unsigned* __restrict__ csum) {
    int c = blockIdx.x * blockDim.x + threadIdx.x;
    int nchunks = (N + chunk - 1) / chunk;
    if (c < nchunks) {
        int lo = c * chunk, hi = lo + chunk; if (hi > N) hi = N;
        unsigned s = 0;
        for (int i = lo; i < hi; ++i) s += deg[i];
        csum[c] = s;
    }
}

__global__ __launch_bounds__(1024) void k_scanchunks(unsigned* __restrict__ csum, int nchunks) {
    __shared__ unsigned sh[1024];
    int t = threadIdx.x;
    unsigned v = (t < nchunks) ? csum[t] : 0u;
    sh[t] = v;
    __syncthreads();
    for (int ofs = 1; ofs < 1024; ofs <<= 1) {
        unsigned p = (t >= ofs) ? sh[t - ofs] : 0u;
        __syncthreads();
        sh[t] += p;
        __syncthreads();
    }
    if (t < nchunks) csum[t] = sh[t] - v;  // exclusive base per chunk
}

__global__ void k_writeptr(const unsigned* __restrict__ deg, const unsigned* __restrict__ csum,
                           int N, int chunk, int* __restrict__ rowptr, int* __restrict__ cursor) {
    int c = blockIdx.x * blockDim.x + threadIdx.x;
    int nchunks = (N + chunk - 1) / chunk;
    if (c < nchunks) {
        int lo = c * chunk, hi = lo + chunk; if (hi > N) hi = N;
        unsigned run = csum[c];
        for (int i = lo; i < hi; ++i) {
            rowptr[i] = (int)run;
            cursor[i] = (int)run;
            run += deg[i];
        }
        if (hi == N) rowptr[N] = (int)run;
    }
}

// bucket-fill: er[pos] = {frm, norm} grouped by target node
__global__ void k_fill(const int* __restrict__ frm, const int* __restrict__ to,
                       const float* __restrict__ w, const float* __restrict__ dis,
                       int E, int* __restrict__ cursor, int2* __restrict__ er) {
    int st = gridDim.x * blockDim.x;
    for (int e = blockIdx.x * blockDim.x + threadIdx.x; e < E; e += st) {
        int f = frm[e], t = to[e];
        float nv = dis[f] * dis[t] * w[e];
        int pos = atomicAdd(&cursor[t], 1);
        int2 r; r.x = f; r.y = __float_as_int(nv);
        er[pos] = r;
    }
}

// x = emb; out0[0:N*D) = emb0; out1 (concat tensor) cols 0..63 = emb0
__global__ void k_emb_init(const float* __restrict__ emb, float* __restrict__ x,
                           float* __restrict__ out, int N) {
    int total = N * (D / 4);
    int st = gridDim.x * blockDim.x;
    const float4* e4 = (const float4*)emb;
    float4* x4 = (float4*)x;
    float4* o4 = (float4*)out;
    for (int j = blockIdx.x * blockDim.x + threadIdx.x; j < total; j += st) {
        float4 v = e4[j];
        x4[j] = v;
        o4[j] = v;                              // output 0: emb0
        int i = j >> 4;
        int c = j & 15;
        o4[(size_t)N * (D / 4) + (size_t)i * 32 + c] = v;  // output 1 cols 0..63
    }
}

// fused per-layer: one wave per node.
// g = sum_e norm_e * x[frm_e]; s = sum_e norm_e;
// x_out = leaky_relu((g+x)@W1^T + (g*x)@W2^T + (s+1)*b1 + s*b2)
#define WP 65  // padded LDS stride: conflict-free writes (stride 65) and reads (stride 1)
__global__ __launch_bounds__(256) void k_layer(
        const int* __restrict__ rowptr, const int2* __restrict__ er,
        const float* __restrict__ xin,
        const float* __restrict__ W1, const float* __restrict__ b1,
        const float* __restrict__ W2, const float* __restrict__ b2,
        int N, float* __restrict__ xout, int ostride) {
    __shared__ float w1t[D * WP];
    __shared__ float w2t[D * WP];
    __shared__ float b1s[D];
    __shared__ float b2s[D];
    for (int idx = threadIdx.x; idx < D * D; idx += blockDim.x) {
        int r = idx >> 6, c = idx & 63;
        w1t[c * WP + r] = W1[idx];   // transposed store, padded -> no bank conflicts
        w2t[c * WP + r] = W2[idx];
    }
    if (threadIdx.x < D) {
        b1s[threadIdx.x] = b1[threadIdx.x];
        b2s[threadIdx.x] = b2[threadIdx.x];
    }
    __syncthreads();
    int lane = threadIdx.x & 63;
    int wid = (blockIdx.x * blockDim.x + threadIdx.x) >> 6;
    int nw = (gridDim.x * blockDim.x) >> 6;
    float bb1 = b1s[lane], bb2 = b2s[lane];
    for (int i = wid; i < N; i += nw) {
        int e = rowptr[i], e1 = rowptr[i + 1];
        float g0 = 0.0f, g1 = 0.0f, g2 = 0.0f, g3 = 0.0f, sv = 0.0f;
        // unroll x4: 4 independent gathers in flight (edge records are
        // wave-uniform 8B loads -> L1 broadcast, consecutive -> L1 hits)
        for (; e + 4 <= e1; e += 4) {
            int2 r0 = er[e + 0];
            int2 r1 = er[e + 1];
            int2 r2 = er[e + 2];
            int2 r3 = er[e + 3];
            float v0 = xin[((size_t)r0.x << 6) + lane];
            float v1 = xin[((size_t)r1.x << 6) + lane];
            float v2 = xin[((size_t)r2.x << 6) + lane];
            float v3 = xin[((size_t)r3.x << 6) + lane];
            float n0 = __int_as_float(r0.y), n1 = __int_as_float(r1.y);
            float n2 = __int_as_float(r2.y), n3 = __int_as_float(r3.y);
            g0 = fmaf(n0, v0, g0);
            g1 = fmaf(n1, v1, g1);
            g2 = fmaf(n2, v2, g2);
            g3 = fmaf(n3, v3, g3);
            sv += (n0 + n1) + (n2 + n3);
        }
        for (; e < e1; ++e) {
            int2 r0 = er[e];
            float n0 = __int_as_float(r0.y);
            g0 = fmaf(n0, xin[((size_t)r0.x << 6) + lane], g0);
            sv += n0;
        }
        float gacc = (g0 + g1) + (g2 + g3);
        float xv = xin[((size_t)i << 6) + lane];
        float h1 = xv + gacc;
        float h2 = xv * gacc;
        float acc = (sv + 1.0f) * bb1 + sv * bb2;
#pragma unroll
        for (int c = 0; c < D; ++c) {
            acc = fmaf(__shfl(h1, c), w1t[c * WP + lane], acc);
            acc = fmaf(__shfl(h2, c), w2t[c * WP + lane], acc);
        }
        float v = acc > 0.0f ? acc : 0.01f * acc;
        xout[(size_t)i * ostride + lane] = v;
    }
}

extern "C" void kernel_launch(void* const* d_in, const int* in_sizes, int n_in,
                              void* d_out, int out_size, void* d_ws, size_t ws_size,
                              hipStream_t stream) {
    const int* eidx = (const int*)d_in[0];
    const float* w = (const float*)d_in[1];
    const float* emb = (const float*)d_in[2];
    const float* W1 = (const float*)d_in[3];
    const float* b1 = (const float*)d_in[4];
    const float* W2 = (const float*)d_in[5];
    const float* b2 = (const float*)d_in[6];

    int E = in_sizes[1];
    int N = in_sizes[2] / D;
    int L = in_sizes[3] / (D * D);
    const int* frm = eidx;
    const int* to = eidx + E;

    char* ws = (char*)d_ws;
    size_t off = 0;
    float* x0 = (float*)(ws + off);     off += align256((size_t)N * D * 4);
    float* x1 = (float*)(ws + off);     off += align256((size_t)N * D * 4);
    int2* er = (int2*)(ws + off);       off += align256((size_t)E * 8);
    int* rowptr = (int*)(ws + off);     off += align256((size_t)(N + 1) * 4);
    int* cursor = (int*)(ws + off);     off += align256((size_t)N * 4);
    unsigned* deg = (unsigned*)(ws + off); off += align256((size_t)N * 4);
    float* dis = (float*)(ws + off);    off += align256((size_t)N * 4);
    unsigned* csum = (unsigned*)(ws + off); off += align256(4096);

    float* out = (float*)d_out;

    int chunk = (N + 1023) >> 10;                 // nchunks <= 1024
    int nchunks = (N + chunk - 1) / chunk;

    hipMemsetAsync(deg, 0, (size_t)N * 4, stream);

    k_deg<<<2048, 256, 0, stream>>>(to, E, deg);
    k_dis<<<(N + 255) / 256, 256, 0, stream>>>(deg, N, dis);
    k_chunksum<<<(nchunks + 255) / 256, 256, 0, stream>>>(deg, N, chunk, csum);
    k_scanchunks<<<1, 1024, 0, stream>>>(csum, nchunks);
    k_writeptr<<<(nchunks + 255) / 256, 256, 0, stream>>>(deg, csum, N, chunk, rowptr, cursor);
    k_fill<<<2048, 256, 0, stream>>>(frm, to, w, dis, E, cursor, er);
    k_emb_init<<<2048, 256, 0, stream>>>(emb, x0, out, N);

    float* xin = x0;
    float* xalt = x1;
    for (int l = 0; l < L; ++l) {
        float* optr;
        int ostride;
        if (l == L - 1) {
            optr = out + (size_t)N * D + D;  // output 1, cols 64..127
            ostride = 2 * D;
        } else {
            optr = xalt;
            ostride = D;
        }
        k_layer<<<2048, 256, 0, stream>>>(rowptr, er, xin,
                                          W1 + (size_t)l * D * D, b1 + (size_t)l * D,
                                          W2 + (size_t)l * D * D, b2 + (size_t)l * D,
                                          N, optr, ostride);
        float* t = xin; xin = xalt; xalt = t;
    }
}

// Round 5
// 477.149 us; speedup vs baseline: 3.5180x; 2.1500x over previous
//
#include <hip/hip_runtime.h>
#include <hip/hip_fp16.h>
#include <math.h>

#define D 64

typedef __attribute__((ext_vector_type(8))) _Float16 f16x8;
typedef __attribute__((ext_vector_type(4))) float f32x4;

static inline size_t align256(size_t x) { return (x + 255) & ~(size_t)255; }

__global__ void k_deg(const int* __restrict__ to, int E, unsigned* __restrict__ deg) {
    int st = gridDim.x * blockDim.x;
    for (int e = blockIdx.x * blockDim.x + threadIdx.x; e < E; e += st)
        atomicAdd(&deg[to[e]], 1u);
}

__global__ void k_dis(const unsigned* __restrict__ deg, int N, float* __restrict__ dis) {
    int n = blockIdx.x * blockDim.x + threadIdx.x;
    if (n < N) {
        unsigned dg = deg[n];
        dis[n] = dg ? 1.0f / sqrtf((float)dg) : 0.0f;
    }
}

// ---- chunked exclusive scan of deg -> rowptr/cursor ----
__global__ void k_chunksum(const unsigned* __restrict__ deg, int N, int chunk,
                           unsigned* __restrict__ csum) {
    int c = blockIdx.x * blockDim.x + threadIdx.x;
    int nchunks = (N + chunk - 1) / chunk;
    if (c < nchunks) {
        int lo = c * chunk, hi = lo + chunk; if (hi > N) hi = N;
        unsigned s = 0;
        for (int i = lo; i < hi; ++i) s += deg[i];
        csum[c] = s;
    }
}

__global__ __launch_bounds__(1024) void k_scanchunks(unsigned* __restrict__ csum, int nchunks) {
    __shared__ unsigned sh[1024];
    int t = threadIdx.x;
    unsigned v = (t < nchunks) ? csum[t] : 0u;
    sh[t] = v;
    __syncthreads();
    for (int ofs = 1; ofs < 1024; ofs <<= 1) {
        unsigned p = (t >= ofs) ? sh[t - ofs] : 0u;
        __syncthreads();
        sh[t] += p;
        __syncthreads();
    }
    if (t < nchunks) csum[t] = sh[t] - v;
}

__global__ void k_writeptr(const unsigned* __restrict__ deg, const unsigned* __restrict__ csum,
                           int N, int chunk, int* __restrict__ rowptr, int* __restrict__ cursor) {
    int c = blockIdx.x * blockDim.x + threadIdx.x;
    int nchunks = (N + chunk - 1) / chunk;
    if (c < nchunks) {
        int lo = c * chunk, hi = lo + chunk; if (hi > N) hi = N;
        unsigned run = csum[c];
        for (int i = lo; i < hi; ++i) {
            rowptr[i] = (int)run;
            cursor[i] = (int)run;
            run += deg[i];
        }
        if (hi == N) rowptr[N] = (int)run;
    }
}

// bucket-fill: er[pos] = {frm, norm} grouped by target node
__global__ void k_fill(const int* __restrict__ frm, const int* __restrict__ to,
                       const float* __restrict__ w, const float* __restrict__ dis,
                       int E, int* __restrict__ cursor, int2* __restrict__ er) {
    int st = gridDim.x * blockDim.x;
    for (int e = blockIdx.x * blockDim.x + threadIdx.x; e < E; e += st) {
        int f = frm[e], t = to[e];
        float nv = dis[f] * dis[t] * w[e];
        int pos = atomicAdd(&cursor[t], 1);
        int2 r; r.x = f; r.y = __float_as_int(nv);
        er[pos] = r;
    }
}

// emb -> x (fp16), out0 = emb0, out1 cols 0..63 = emb0
__global__ void k_emb_init(const float* __restrict__ emb, __half* __restrict__ x,
                           float* __restrict__ out, int N) {
    int total = N * 16;  // float4 units
    int st = gridDim.x * blockDim.x;
    const float4* e4 = (const float4*)emb;
    float4* o4 = (float4*)out;
    __half2* xh = (__half2*)x;
    for (int j = blockIdx.x * blockDim.x + threadIdx.x; j < total; j += st) {
        float4 v = e4[j];
        o4[j] = v;                                       // output 0
        int i = j >> 4, c = j & 15;
        o4[(size_t)N * 16 + (size_t)i * 32 + c] = v;     // output 1 cols 0..63
        xh[2 * j]     = __floats2half2_rn(v.x, v.y);
        xh[2 * j + 1] = __floats2half2_rn(v.z, v.w);
    }
}

// segmented gather: each wave owns edges [lo,hi); g[n] = sum norm*x[frm], s[n] = sum norm.
// Plain stores for wave-exclusive nodes; atomics only for chunk-boundary nodes.
__global__ __launch_bounds__(256) void k_gather(
        const int* __restrict__ rowptr, const int2* __restrict__ er,
        const __half* __restrict__ xin, int N, int E, int epw,
        float* __restrict__ g, float* __restrict__ s) {
    int lane = threadIdx.x & 63;
    int wid = (blockIdx.x * blockDim.x + threadIdx.x) >> 6;
    long lo_l = (long)wid * epw;
    if (lo_l >= E) return;
    int lo = (int)lo_l;
    int hi = lo + epw; if (hi > E) hi = E;
    // smallest n with rowptr[n+1] > lo
    int a = 0, b = N - 1;
    while (a < b) { int m = (a + b) >> 1; if (rowptr[m + 1] > lo) b = m; else a = m + 1; }
    int n = a;
    int nstart = rowptr[n], nend = rowptr[n + 1];
    float gacc = 0.0f, sv = 0.0f;
    int e = lo;
    while (true) {
        int stop = nend < hi ? nend : hi;
        for (; e + 8 <= stop; e += 8) {
            int2 r0 = er[e+0]; int2 r1 = er[e+1]; int2 r2 = er[e+2]; int2 r3 = er[e+3];
            int2 r4 = er[e+4]; int2 r5 = er[e+5]; int2 r6 = er[e+6]; int2 r7 = er[e+7];
            float v0 = __half2float(xin[((size_t)r0.x << 6) + lane]);
            float v1 = __half2float(xin[((size_t)r1.x << 6) + lane]);
            float v2 = __half2float(xin[((size_t)r2.x << 6) + lane]);
            float v3 = __half2float(xin[((size_t)r3.x << 6) + lane]);
            float v4 = __half2float(xin[((size_t)r4.x << 6) + lane]);
            float v5 = __half2float(xin[((size_t)r5.x << 6) + lane]);
            float v6 = __half2float(xin[((size_t)r6.x << 6) + lane]);
            float v7 = __half2float(xin[((size_t)r7.x << 6) + lane]);
            float n0 = __int_as_float(r0.y), n1 = __int_as_float(r1.y);
            float n2 = __int_as_float(r2.y), n3 = __int_as_float(r3.y);
            float n4 = __int_as_float(r4.y), n5 = __int_as_float(r5.y);
            float n6 = __int_as_float(r6.y), n7 = __int_as_float(r7.y);
            gacc = fmaf(n0, v0, gacc); gacc = fmaf(n1, v1, gacc);
            gacc = fmaf(n2, v2, gacc); gacc = fmaf(n3, v3, gacc);
            gacc = fmaf(n4, v4, gacc); gacc = fmaf(n5, v5, gacc);
            gacc = fmaf(n6, v6, gacc); gacc = fmaf(n7, v7, gacc);
            sv += ((n0 + n1) + (n2 + n3)) + ((n4 + n5) + (n6 + n7));
        }
        for (; e + 4 <= stop; e += 4) {
            int2 r0 = er[e+0]; int2 r1 = er[e+1]; int2 r2 = er[e+2]; int2 r3 = er[e+3];
            float v0 = __half2float(xin[((size_t)r0.x << 6) + lane]);
            float v1 = __half2float(xin[((size_t)r1.x << 6) + lane]);
            float v2 = __half2float(xin[((size_t)r2.x << 6) + lane]);
            float v3 = __half2float(xin[((size_t)r3.x << 6) + lane]);
            float n0 = __int_as_float(r0.y), n1 = __int_as_float(r1.y);
            float n2 = __int_as_float(r2.y), n3 = __int_as_float(r3.y);
            gacc = fmaf(n0, v0, gacc); gacc = fmaf(n1, v1, gacc);
            gacc = fmaf(n2, v2, gacc); gacc = fmaf(n3, v3, gacc);
            sv += (n0 + n1) + (n2 + n3);
        }
        for (; e < stop; ++e) {
            int2 r0 = er[e];
            float n0 = __int_as_float(r0.y);
            gacc = fmaf(n0, __half2float(xin[((size_t)r0.x << 6) + lane]), gacc);
            sv += n0;
        }
        if (e == nend) {
            if (nstart < lo) {  // node started in a previous chunk -> shared
                unsafeAtomicAdd(&g[((size_t)n << 6) + lane], gacc);
                if (lane == 0) unsafeAtomicAdd(&s[n], sv);
            } else {
                g[((size_t)n << 6) + lane] = gacc;
                if (lane == 0) s[n] = sv;
            }
            gacc = 0.0f; sv = 0.0f;
            if (e >= hi) break;
            ++n;
            while (rowptr[n + 1] <= e) ++n;  // skip deg-0 nodes
            nstart = rowptr[n]; nend = rowptr[n + 1];
        } else {  // e == hi < nend: node continues into next chunk -> shared
            unsafeAtomicAdd(&g[((size_t)n << 6) + lane], gacc);
            if (lane == 0) unsafeAtomicAdd(&s[n], sv);
            break;
        }
    }
}

// MFMA node update: out = leaky_relu((g+x)@W1^T + (g*x)@W2^T + (s+1)b1 + s*b2)
// 16-node tile per wave iteration; weights as f16 fragments in LDS (per-lane 16B, conflict-free).
__global__ __launch_bounds__(512) void k_update(
        const float* __restrict__ g, const __half* __restrict__ xin,
        const float* __restrict__ s,
        const float* __restrict__ W1, const float* __restrict__ b1,
        const float* __restrict__ W2, const float* __restrict__ b2,
        int N, float* __restrict__ outf, __half* __restrict__ outh, int ostride) {
    // frag index: mat(2) x nt(4) x ks(2) = 16 frags, 64 lanes x 8 f16 each
    __shared__ f16x8 wfrag[16][64];
    int tid = threadIdx.x;
    for (int idx = tid; idx < 16 * 64; idx += blockDim.x) {
        int fr = idx >> 6, l = idx & 63;
        int mat = fr >> 3, nt = (fr >> 1) & 3, ks = fr & 1;
        int j = nt * 16 + (l & 15);
        int kb = ((l >> 4) << 3) + ks * 32;
        const float* src = (mat ? W2 : W1) + j * D + kb;
        f16x8 v;
#pragma unroll
        for (int q = 0; q < 8; ++q) v[q] = (_Float16)src[q];
        wfrag[fr][l] = v;
    }
    __syncthreads();
    int lane = tid & 63;
    int wid = (blockIdx.x * blockDim.x + tid) >> 6;
    int nw = (gridDim.x * blockDim.x) >> 6;
    int L = lane & 15, H = lane >> 4;
    float bb1[4], bb2[4];
#pragma unroll
    for (int nt = 0; nt < 4; ++nt) { bb1[nt] = b1[nt * 16 + L]; bb2[nt] = b2[nt * 16 + L]; }
    int ntiles = N >> 4;  // N assumed multiple of 16 (100000/16 = 6250)
    for (int t = wid; t < ntiles; t += nw) {
        int tb = t << 4;
        // A-frags: lane holds rows tb+L, k = H*8 + q + ks*32
        f16x8 a1[2], a2[2];
#pragma unroll
        for (int ks = 0; ks < 2; ++ks) {
            size_t base = ((size_t)(tb + L) << 6) + (H << 3) + ks * 32;
            f32x4 g0 = *(const f32x4*)(g + base);
            f32x4 g1 = *(const f32x4*)(g + base + 4);
            f16x8 xv = *(const f16x8*)(xin + base);
            f16x8 h1v, h2v;
#pragma unroll
            for (int q = 0; q < 4; ++q) {
                float gq = g0[q], xq = (float)xv[q];
                h1v[q] = (_Float16)(gq + xq);
                h2v[q] = (_Float16)(gq * xq);
            }
#pragma unroll
            for (int q = 0; q < 4; ++q) {
                float gq = g1[q], xq = (float)xv[4 + q];
                h1v[4 + q] = (_Float16)(gq + xq);
                h2v[4 + q] = (_Float16)(gq * xq);
            }
            a1[ks] = h1v; a2[ks] = h2v;
        }
        // output rows this lane writes: tb + H*4 + r
        float sr[4];
#pragma unroll
        for (int r = 0; r < 4; ++r) sr[r] = s[tb + (H << 2) + r];
#pragma unroll
        for (int nt = 0; nt < 4; ++nt) {
            f32x4 acc;
#pragma unroll
            for (int r = 0; r < 4; ++r) acc[r] = (sr[r] + 1.0f) * bb1[nt] + sr[r] * bb2[nt];
            acc = __builtin_amdgcn_mfma_f32_16x16x32_f16(a1[0], wfrag[nt * 2 + 0][lane], acc, 0, 0, 0);
            acc = __builtin_amdgcn_mfma_f32_16x16x32_f16(a1[1], wfrag[nt * 2 + 1][lane], acc, 0, 0, 0);
            acc = __builtin_amdgcn_mfma_f32_16x16x32_f16(a2[0], wfrag[8 + nt * 2 + 0][lane], acc, 0, 0, 0);
            acc = __builtin_amdgcn_mfma_f32_16x16x32_f16(a2[1], wfrag[8 + nt * 2 + 1][lane], acc, 0, 0, 0);
#pragma unroll
            for (int r = 0; r < 4; ++r) {
                float v = acc[r];
                v = v > 0.0f ? v : 0.01f * v;
                int row = tb + (H << 2) + r;
                if (outf) outf[(size_t)row * ostride + nt * 16 + L] = v;
                else      outh[((size_t)row << 6) + nt * 16 + L] = __float2half(v);
            }
        }
    }
}

extern "C" void kernel_launch(void* const* d_in, const int* in_sizes, int n_in,
                              void* d_out, int out_size, void* d_ws, size_t ws_size,
                              hipStream_t stream) {
    const int* eidx = (const int*)d_in[0];
    const float* w = (const float*)d_in[1];
    const float* emb = (const float*)d_in[2];
    const float* W1 = (const float*)d_in[3];
    const float* b1 = (const float*)d_in[4];
    const float* W2 = (const float*)d_in[5];
    const float* b2 = (const float*)d_in[6];

    int E = in_sizes[1];
    int N = in_sizes[2] / D;
    int L = in_sizes[3] / (D * D);
    const int* frm = eidx;
    const int* to = eidx + E;

    char* ws = (char*)d_ws;
    size_t off = 0;
    __half* x0 = (__half*)(ws + off);   off += align256((size_t)N * D * 2);
    __half* x1 = (__half*)(ws + off);   off += align256((size_t)N * D * 2);
    float* g = (float*)(ws + off);      off += align256((size_t)N * D * 4);
    int2* er = (int2*)(ws + off);       off += align256((size_t)E * 8);
    int* rowptr = (int*)(ws + off);     off += align256((size_t)(N + 1) * 4);
    int* cursor = (int*)(ws + off);     off += align256((size_t)N * 4);
    unsigned* deg = (unsigned*)(ws + off); off += align256((size_t)N * 4);
    float* dis = (float*)(ws + off);    off += align256((size_t)N * 4);
    float* s = (float*)(ws + off);      off += align256((size_t)N * 4);
    unsigned* csum = (unsigned*)(ws + off); off += align256(4096);

    float* out = (float*)d_out;

    int chunk = (N + 1023) >> 10;
    int nchunks = (N + chunk - 1) / chunk;
    const int NWAVES = 8192;
    int epw = (E + NWAVES - 1) / NWAVES;

    hipMemsetAsync(deg, 0, (size_t)N * 4, stream);

    k_deg<<<2048, 256, 0, stream>>>(to, E, deg);
    k_dis<<<(N + 255) / 256, 256, 0, stream>>>(deg, N, dis);
    k_chunksum<<<(nchunks + 255) / 256, 256, 0, stream>>>(deg, N, chunk, csum);
    k_scanchunks<<<1, 1024, 0, stream>>>(csum, nchunks);
    k_writeptr<<<(nchunks + 255) / 256, 256, 0, stream>>>(deg, csum, N, chunk, rowptr, cursor);
    k_fill<<<2048, 256, 0, stream>>>(frm, to, w, dis, E, cursor, er);
    k_emb_init<<<2048, 256, 0, stream>>>(emb, x0, out, N);

    __half* xin = x0;
    __half* xalt = x1;
    for (int l = 0; l < L; ++l) {
        hipMemsetAsync(g, 0, (size_t)N * D * 4, stream);
        hipMemsetAsync(s, 0, (size_t)N * 4, stream);
        k_gather<<<NWAVES / 4, 256, 0, stream>>>(rowptr, er, xin, N, E, epw, g, s);
        float* outf = nullptr;
        __half* outh = xalt;
        int ostride = D;
        if (l == L - 1) {
            outf = out + (size_t)N * D + D;  // output 1, cols 64..127
            outh = nullptr;
            ostride = 2 * D;
        }
        k_update<<<512, 512, 0, stream>>>(g, xin, s,
                                          W1 + (size_t)l * D * D, b1 + (size_t)l * D,
                                          W2 + (size_t)l * D * D, b2 + (size_t)l * D,
                                          N, outf, outh, ostride);
        __half* t = xin; xin = xalt; xalt = t;
    }
}